// Round 13
// baseline (2146.487 us; speedup 1.0000x reference)
//
#include <hip/hip_runtime.h>
#include <math.h>

#define VOCAB  32000
#define EMB    256
#define HID    512
#define MAXLEN 512
#define BATCH  128
#define NCLASS 2

#define NBG 8     // batch groups (16 rows each)
#define NJG 4     // col groups (128 cols each)
#define RPB 16    // rows per block
#define CPB 128   // cols per block
#define KP  520   // padded k stride (bf16 elems) for Wb/hsb rows
#define SSP 136   // hss row stride (bf16 elems)

typedef __attribute__((ext_vector_type(8))) short bf16x8;
typedef __attribute__((ext_vector_type(4))) float f32x4;

// round-to-nearest-even fp32 -> bf16 (bit form)
__device__ __forceinline__ unsigned short f2b_bits(unsigned int u) {
    return (unsigned short)((u + 0x7fffu + ((u >> 16) & 1u)) >> 16);
}

// ---------------------------------------------------------------------------
// Kernel A: embW[v][j] = b_h[j] + sum_e emb[v][e] * W_ih[e][j]  (fp32, exact)
// (unchanged — ~70 us)
// ---------------------------------------------------------------------------
__global__ __launch_bounds__(256, 1) void embw_kernel(
    const float* __restrict__ emb, const float* __restrict__ W_ih,
    const float* __restrict__ b_h, float* __restrict__ embW)
{
    __shared__ __align__(16) float aT[EMB][64];
    __shared__ __align__(16) float wS[32][HID];

    const int t    = threadIdx.x;
    const int row0 = blockIdx.x * 64;

    {
        const int row   = t >> 2;
        const int elane = t & 3;
        for (int i = 0; i < 16; ++i) {
            const int e = elane * 4 + i * 16;
            const float4 v = *reinterpret_cast<const float4*>(
                &emb[(size_t)(row0 + row) * EMB + e]);
            aT[e + 0][row] = v.x;
            aT[e + 1][row] = v.y;
            aT[e + 2][row] = v.z;
            aT[e + 3][row] = v.w;
        }
    }

    const int rg = t >> 5;
    const int cg = t & 31;

    float acc[8][16];
    #pragma unroll
    for (int r = 0; r < 8; ++r)
        #pragma unroll
        for (int c = 0; c < 16; ++c) acc[r][c] = 0.f;

    for (int ec = 0; ec < 8; ++ec) {
        __syncthreads();
        {
            const int j4  = (t & 127) * 4;
            const int keb = (t >> 7);
            #pragma unroll
            for (int i = 0; i < 16; ++i) {
                const int ke = keb + i * 2;
                const float4 v = *reinterpret_cast<const float4*>(
                    &W_ih[(size_t)(ec * 32 + ke) * HID + j4]);
                *reinterpret_cast<float4*>(&wS[ke][j4]) = v;
            }
        }
        __syncthreads();

        for (int ke = 0; ke < 32; ++ke) {
            float a8[8];
            *(float4*)&a8[0] = *(const float4*)&aT[ec * 32 + ke][rg * 8];
            *(float4*)&a8[4] = *(const float4*)&aT[ec * 32 + ke][rg * 8 + 4];
            float w16[16];
            #pragma unroll
            for (int q = 0; q < 4; ++q)
                *(float4*)&w16[q * 4] =
                    *(const float4*)&wS[ke][cg * 16 + q * 4];
            #pragma unroll
            for (int r = 0; r < 8; ++r)
                #pragma unroll
                for (int c = 0; c < 16; ++c)
                    acc[r][c] = fmaf(a8[r], w16[c], acc[r][c]);
        }
    }

    float bh[16];
    #pragma unroll
    for (int q = 0; q < 4; ++q)
        *(float4*)&bh[q * 4] = *(const float4*)&b_h[cg * 16 + q * 4];
    #pragma unroll
    for (int r = 0; r < 8; ++r) {
        const size_t orow = (size_t)(row0 + rg * 8 + r) * HID + cg * 16;
        #pragma unroll
        for (int q = 0; q < 4; ++q) {
            float4 v;
            v.x = acc[r][q * 4 + 0] + bh[q * 4 + 0];
            v.y = acc[r][q * 4 + 1] + bh[q * 4 + 1];
            v.z = acc[r][q * 4 + 2] + bh[q * 4 + 2];
            v.w = acc[r][q * 4 + 3] + bh[q * 4 + 3];
            *reinterpret_cast<float4*>(&embW[orow + q * 4]) = v;
        }
    }
}

// ---------------------------------------------------------------------------
// Kernel B: sequential RNN — bf16 MFMA + self-panel-in-LDS + flag pipeline.
// R11 base (32 blocks x 512 thr, bf16 W in LDS [col][KP], MFMA 16x16x32,
// fp32 embW feedforward, fp32 h exchange) with the exchange restructured:
//  * SELF k-panel (own 128 cols) never leaves the CU: epilogue writes h
//    bf16 into hss; next step's self-MFMA reads it with ZERO wait/global.
//  * Central counter replaced by per-(bgrp,jgrp) MONOTONE flags. ONE t0
//    spinner polls the 3 sibling flags (acquire — R4/R11-proven semantics;
//    R7 lesson: never spin in many threads).
//  * Step order: self-MFMA(4 kt) -> wait sibs -> stage 3 panels ->
//    MFMA(12 kt) -> tanh -> publish global + hss -> sync -> release flag.
//    Sibling publish latency hides under self-MFMA + ev gather.
// Safety: full fan-in flags => <=1-step skew => 2-buffer ping-pong safe
//   (same invariant as the central counter). Race-check: hss epilogue
//   writes are separated from all self-MFMA reads by syncs D/E (this
//   step) and H (next step).
// ---------------------------------------------------------------------------
__global__ __launch_bounds__(512, 1) void rnn_kernel(
    const int* __restrict__ inputs, const float* __restrict__ embW,
    const float* __restrict__ W_hh, float* hA, float* hB,
    int* flags)
{
    __shared__ __align__(16) unsigned short Wb[CPB][KP];   // 133,120 B
    __shared__ __align__(16) unsigned short hsb[RPB][KP];  // 16,640 B
    __shared__ __align__(16) unsigned short hss[RPB][SSP]; //  4,352 B

    const int t    = threadIdx.x;
    const int w    = t >> 6;          // wave 0..7 = col-tile
    const int l    = t & 63;
    const int lm   = l & 15;          // MFMA row/col lane index
    const int lk   = l >> 4;          // MFMA k-group / D row group
    const int bid  = blockIdx.x;
    const int bgrp = bid & 7;
    const int jgrp = bid >> 3;
    const int j0   = jgrp * CPB;
    const int r0   = bgrp * RPB;
    const int srow = t >> 5;          // staging row (0..15)
    const int skc  = (t & 31) * 4;    // staging k within panel (0..124)

    // ---- one-time: stage W slice to bf16 LDS [col][k] ----
    {
        const int c  = t & 127;       // local col
        const int kq = t >> 7;        // k quarter
        for (int i = 0; i < 128; i += 4) {
            const int k = kq * 128 + i;
            unsigned int u0 = __builtin_bit_cast(unsigned int,
                                W_hh[(size_t)(k + 0) * HID + j0 + c]);
            unsigned int u1 = __builtin_bit_cast(unsigned int,
                                W_hh[(size_t)(k + 1) * HID + j0 + c]);
            unsigned int u2 = __builtin_bit_cast(unsigned int,
                                W_hh[(size_t)(k + 2) * HID + j0 + c]);
            unsigned int u3 = __builtin_bit_cast(unsigned int,
                                W_hh[(size_t)(k + 3) * HID + j0 + c]);
            unsigned int p0 = (unsigned int)f2b_bits(u0) |
                              ((unsigned int)f2b_bits(u1) << 16);
            unsigned int p1 = (unsigned int)f2b_bits(u2) |
                              ((unsigned int)f2b_bits(u3) << 16);
            *(unsigned long long*)&Wb[c][k] =
                (unsigned long long)p0 | ((unsigned long long)p1 << 32);
        }
    }
    // ---- zero hss (h(0) = 0 for the self panel) ----
    for (int i = t; i < RPB * SSP / 4; i += 512)
        *(unsigned long long*)&((unsigned short*)hss)[i * 4] = 0ull;
    __syncthreads();

    for (int ts = 0; ts < MAXLEN; ++ts) {
        const float* hc = (ts & 1) ? hB : hA;
        float*       hn = (ts & 1) ? hA : hB;

        // ---- feedforward gather (fp32; hides under self-MFMA/spin) ----
        float ev[4];
        #pragma unroll
        for (int i = 0; i < 4; ++i) {
            const int r   = lk * 4 + i;
            const int tok = inputs[(r0 + r) * MAXLEN + ts];
            ev[i] = embW[(size_t)tok * HID + j0 + w * 16 + lm];
        }

        // ---- self-panel MFMA (k = jgrp*128 .. +127, A from hss) ----
        f32x4 ae = {0.f, 0.f, 0.f, 0.f};
        f32x4 ao = {0.f, 0.f, 0.f, 0.f};
        {
            const int ktb = jgrp * 4;
            #pragma unroll
            for (int q = 0; q < 4; q += 2) {
                const bf16x8 a0 = *(const bf16x8*)&hss[lm][(q) * 32 + lk * 8];
                const bf16x8 b0 = *(const bf16x8*)&Wb[w * 16 + lm][(ktb + q) * 32 + lk * 8];
                ae = __builtin_amdgcn_mfma_f32_16x16x32_bf16(a0, b0, ae, 0, 0, 0);
                const bf16x8 a1 = *(const bf16x8*)&hss[lm][(q + 1) * 32 + lk * 8];
                const bf16x8 b1 = *(const bf16x8*)&Wb[w * 16 + lm][(ktb + q + 1) * 32 + lk * 8];
                ao = __builtin_amdgcn_mfma_f32_16x16x32_bf16(a1, b1, ao, 0, 0, 0);
            }
        }

        // ---- D: wait for the 3 sibling flags (t0 only, acquire) ----
        if (t == 0) {
            #pragma unroll
            for (int pi = 1; pi < 4; ++pi) {
                const int p = (jgrp + pi) & 3;
                while (__hip_atomic_load(&flags[bgrp * NJG + p],
                                         __ATOMIC_ACQUIRE,
                                         __HIP_MEMORY_SCOPE_AGENT) < ts) {
                    __builtin_amdgcn_s_sleep(1);
                }
            }
        }
        __syncthreads();

        // ---- E: stage the 3 sibling panels (fp32 -> bf16 LDS) ----
        {
            unsigned long long d[3][2];
            #pragma unroll
            for (int pi = 1; pi < 4; ++pi) {
                const int p = (jgrp + pi) & 3;
                const unsigned long long* src = (const unsigned long long*)
                    &hc[(size_t)(r0 + srow) * HID + p * 128 + skc];
                d[pi - 1][0] = __hip_atomic_load(src + 0,
                    __ATOMIC_RELAXED, __HIP_MEMORY_SCOPE_AGENT);
                d[pi - 1][1] = __hip_atomic_load(src + 1,
                    __ATOMIC_RELAXED, __HIP_MEMORY_SCOPE_AGENT);
            }
            #pragma unroll
            for (int pi = 1; pi < 4; ++pi) {
                const int p = (jgrp + pi) & 3;
                const unsigned long long lo = d[pi - 1][0];
                const unsigned long long hi = d[pi - 1][1];
                unsigned int q0 = (unsigned int)f2b_bits((unsigned int)lo) |
                    ((unsigned int)f2b_bits((unsigned int)(lo >> 32)) << 16);
                unsigned int q1 = (unsigned int)f2b_bits((unsigned int)hi) |
                    ((unsigned int)f2b_bits((unsigned int)(hi >> 32)) << 16);
                *(unsigned long long*)&hsb[srow][p * 128 + skc] =
                    (unsigned long long)q0 | ((unsigned long long)q1 << 32);
            }
        }
        __syncthreads();

        // ---- F: remaining 12 k-tiles (A from hsb) ----
        #pragma unroll
        for (int pi = 1; pi < 4; ++pi) {
            const int p   = (jgrp + pi) & 3;
            const int ktb = p * 4;
            #pragma unroll
            for (int q = 0; q < 4; q += 2) {
                const bf16x8 a0 = *(const bf16x8*)&hsb[lm][(ktb + q) * 32 + lk * 8];
                const bf16x8 b0 = *(const bf16x8*)&Wb[w * 16 + lm][(ktb + q) * 32 + lk * 8];
                ae = __builtin_amdgcn_mfma_f32_16x16x32_bf16(a0, b0, ae, 0, 0, 0);
                const bf16x8 a1 = *(const bf16x8*)&hsb[lm][(ktb + q + 1) * 32 + lk * 8];
                const bf16x8 b1 = *(const bf16x8*)&Wb[w * 16 + lm][(ktb + q + 1) * 32 + lk * 8];
                ao = __builtin_amdgcn_mfma_f32_16x16x32_bf16(a1, b1, ao, 0, 0, 0);
            }
        }
        const f32x4 cc = ae + ao;

        // ---- G: tanh + publish global (fp32) + hss self panel (bf16) ----
        #pragma unroll
        for (int i = 0; i < 4; ++i) {
            const float s = tanhf(cc[i] + ev[i]);
            __hip_atomic_store(
                &hn[(size_t)(r0 + lk * 4 + i) * HID + j0 + w * 16 + lm], s,
                __ATOMIC_RELAXED, __HIP_MEMORY_SCOPE_AGENT);
            hss[lk * 4 + i][w * 16 + lm] =
                f2b_bits(__builtin_bit_cast(unsigned int, s));
        }
        __syncthreads();   // H: vmcnt drain (publish) + hss writes complete

        // ---- release our flag (monotone; release orders after drain) ----
        if (t == 0)
            __hip_atomic_store(&flags[bgrp * NJG + jgrp], ts + 1,
                               __ATOMIC_RELEASE, __HIP_MEMORY_SCOPE_AGENT);
    }
    // final h in hA (MAXLEN even)
}

// ---------------------------------------------------------------------------
// Kernel C: logits = hA @ W_out + b_out, sigmoid. Tiny. (fp32, unchanged)
// ---------------------------------------------------------------------------
__global__ void head_kernel(const float* __restrict__ h_final,
                            const float* __restrict__ W_out,
                            const float* __restrict__ b_out,
                            float* __restrict__ out)
{
    const int t = threadIdx.x;
    const int b = t >> 1, c = t & 1;
    float acc = b_out[c];
    for (int k = 0; k < HID; ++k)
        acc = fmaf(h_final[(size_t)b * HID + k], W_out[k * NCLASS + c], acc);
    out[t] = 1.f / (1.f + expf(-acc));
}

// ---------------------------------------------------------------------------
extern "C" void kernel_launch(void* const* d_in, const int* in_sizes, int n_in,
                              void* d_out, int out_size, void* d_ws,
                              size_t ws_size, hipStream_t stream)
{
    const int*   inputs = (const int*)  d_in[0];
    const float* emb    = (const float*)d_in[1];
    const float* W_ih   = (const float*)d_in[2];
    const float* W_hh   = (const float*)d_in[3];
    const float* b_h    = (const float*)d_in[4];
    const float* W_out  = (const float*)d_in[5];
    const float* b_out  = (const float*)d_in[6];
    float* out = (float*)d_out;

    // ws layout: embW 64 MB | hA 256 KB | hB 256 KB | flags 128 B
    float* embW  = (float*)d_ws;
    float* hA    = embW + (size_t)VOCAB * HID;
    float* hB    = hA + (size_t)BATCH * HID;
    int*   flags = (int*)(hB + (size_t)BATCH * HID);

    // per-launch re-init (graph-capture-safe, deterministic)
    hipMemsetAsync(hA, 0, (size_t)BATCH * HID * sizeof(float), stream);
    hipMemsetAsync(flags, 0, (size_t)NBG * NJG * sizeof(int), stream);

    embw_kernel<<<VOCAB / 64, 256, 0, stream>>>(emb, W_ih, b_h, embW);
    rnn_kernel<<<NBG * NJG, 512, 0, stream>>>(inputs, embW, W_hh,
                                              hA, hB, flags);
    head_kernel<<<1, 256, 0, stream>>>(hA, W_out, b_out, out);
}

// Round 14
// 1870.544 us; speedup vs baseline: 1.1475x; 1.1475x over previous
//
#include <hip/hip_runtime.h>
#include <math.h>

#define VOCAB  32000
#define EMB    256
#define HID    512
#define MAXLEN 512
#define BATCH  128
#define NCLASS 2

#define NBG 8     // batch groups (16 rows each)
#define NJG 4     // col groups (128 cols each)
#define RPB 16    // rows per block
#define CPB 128   // cols per block
#define KP  520   // padded k stride (bf16 elems) for Wb/hsb rows

typedef __attribute__((ext_vector_type(8))) short bf16x8;
typedef __attribute__((ext_vector_type(4))) float f32x4;

// round-to-nearest-even fp32 -> bf16 (bit form)
__device__ __forceinline__ unsigned short f2b_bits(unsigned int u) {
    return (unsigned short)((u + 0x7fffu + ((u >> 16) & 1u)) >> 16);
}

// ---------------------------------------------------------------------------
// Kernel A: embW[v][j] = b_h[j] + sum_e emb[v][e] * W_ih[e][j]  (fp32, exact)
// (unchanged — ~70 us)
// ---------------------------------------------------------------------------
__global__ __launch_bounds__(256, 1) void embw_kernel(
    const float* __restrict__ emb, const float* __restrict__ W_ih,
    const float* __restrict__ b_h, float* __restrict__ embW)
{
    __shared__ __align__(16) float aT[EMB][64];
    __shared__ __align__(16) float wS[32][HID];

    const int t    = threadIdx.x;
    const int row0 = blockIdx.x * 64;

    {
        const int row   = t >> 2;
        const int elane = t & 3;
        for (int i = 0; i < 16; ++i) {
            const int e = elane * 4 + i * 16;
            const float4 v = *reinterpret_cast<const float4*>(
                &emb[(size_t)(row0 + row) * EMB + e]);
            aT[e + 0][row] = v.x;
            aT[e + 1][row] = v.y;
            aT[e + 2][row] = v.z;
            aT[e + 3][row] = v.w;
        }
    }

    const int rg = t >> 5;
    const int cg = t & 31;

    float acc[8][16];
    #pragma unroll
    for (int r = 0; r < 8; ++r)
        #pragma unroll
        for (int c = 0; c < 16; ++c) acc[r][c] = 0.f;

    for (int ec = 0; ec < 8; ++ec) {
        __syncthreads();
        {
            const int j4  = (t & 127) * 4;
            const int keb = (t >> 7);
            #pragma unroll
            for (int i = 0; i < 16; ++i) {
                const int ke = keb + i * 2;
                const float4 v = *reinterpret_cast<const float4*>(
                    &W_ih[(size_t)(ec * 32 + ke) * HID + j4]);
                *reinterpret_cast<float4*>(&wS[ke][j4]) = v;
            }
        }
        __syncthreads();

        for (int ke = 0; ke < 32; ++ke) {
            float a8[8];
            *(float4*)&a8[0] = *(const float4*)&aT[ec * 32 + ke][rg * 8];
            *(float4*)&a8[4] = *(const float4*)&aT[ec * 32 + ke][rg * 8 + 4];
            float w16[16];
            #pragma unroll
            for (int q = 0; q < 4; ++q)
                *(float4*)&w16[q * 4] =
                    *(const float4*)&wS[ke][cg * 16 + q * 4];
            #pragma unroll
            for (int r = 0; r < 8; ++r)
                #pragma unroll
                for (int c = 0; c < 16; ++c)
                    acc[r][c] = fmaf(a8[r], w16[c], acc[r][c]);
        }
    }

    float bh[16];
    #pragma unroll
    for (int q = 0; q < 4; ++q)
        *(float4*)&bh[q * 4] = *(const float4*)&b_h[cg * 16 + q * 4];
    #pragma unroll
    for (int r = 0; r < 8; ++r) {
        const size_t orow = (size_t)(row0 + rg * 8 + r) * HID + cg * 16;
        #pragma unroll
        for (int q = 0; q < 4; ++q) {
            float4 v;
            v.x = acc[r][q * 4 + 0] + bh[q * 4 + 0];
            v.y = acc[r][q * 4 + 1] + bh[q * 4 + 1];
            v.z = acc[r][q * 4 + 2] + bh[q * 4 + 2];
            v.w = acc[r][q * 4 + 3] + bh[q * 4 + 3];
            *reinterpret_cast<float4*>(&embW[orow + q * 4]) = v;
        }
    }
}

// ---------------------------------------------------------------------------
// Kernel B: sequential RNN — R11 structure (bf16 MFMA, central-counter
// barrier) + B-fragments (W) held in VGPRs across the ts-loop.
// R12 lesson: protocol variants don't beat the R11 central counter —
//   exchange is agent-visibility-bound. Reverted to R11 verbatim.
// New: per-thread 16 named bf16x8 B-frags loaded ONCE from Wb after
//   staging. W is ts-invariant, so the per-step MFMA path reads only A
//   (16 ds_read_b128/thread-wave vs 32) and B-side bank conflicts vanish.
//   (R5/R6 scar: compiler may sink these LDS loads into the loop; failure
//   mode = R11's code. Falsifiable via VGPR_Count: ~88 sunk, ~160+ held.)
// 32 blocks x 512 threads: block (bgrp=bid&7, jgrp=bid>>3) owns 16 rows x
//   128 cols. Siblings of bgrp = same XCD under round-robin (perf-only).
// MFMA 16x16x32: A lane: row=l&15, k=(l>>4)*8+j; B lane: col=l&15; D lane:
//   row=(l>>4)*4+i, col=l&15 (guide §3, m89-verified; R11/R12 ref-passed).
// ---------------------------------------------------------------------------
__global__ __launch_bounds__(512, 1) void rnn_kernel(
    const int* __restrict__ inputs, const float* __restrict__ embW,
    const float* __restrict__ W_hh, float* hA, float* hB,
    int* bar)
{
    __shared__ __align__(16) unsigned short Wb[CPB][KP];   // 133,120 B
    __shared__ __align__(16) unsigned short hsb[RPB][KP];  // 16,640 B

    const int t    = threadIdx.x;
    const int w    = t >> 6;          // wave 0..7 = col-tile
    const int l    = t & 63;
    const int lm   = l & 15;          // MFMA row/col lane index
    const int lk   = l >> 4;          // MFMA k-group / D row group
    const int bid  = blockIdx.x;
    const int bgrp = bid & 7;
    const int jgrp = bid >> 3;
    const int j0   = jgrp * CPB;
    const int r0   = bgrp * RPB;

    // ---- one-time: stage W slice to bf16 LDS [col][k] ----
    {
        const int c  = t & 127;       // local col
        const int kq = t >> 7;        // k quarter
        for (int i = 0; i < 128; i += 4) {
            const int k = kq * 128 + i;
            unsigned int u0 = __builtin_bit_cast(unsigned int,
                                W_hh[(size_t)(k + 0) * HID + j0 + c]);
            unsigned int u1 = __builtin_bit_cast(unsigned int,
                                W_hh[(size_t)(k + 1) * HID + j0 + c]);
            unsigned int u2 = __builtin_bit_cast(unsigned int,
                                W_hh[(size_t)(k + 2) * HID + j0 + c]);
            unsigned int u3 = __builtin_bit_cast(unsigned int,
                                W_hh[(size_t)(k + 3) * HID + j0 + c]);
            unsigned int p0 = (unsigned int)f2b_bits(u0) |
                              ((unsigned int)f2b_bits(u1) << 16);
            unsigned int p1 = (unsigned int)f2b_bits(u2) |
                              ((unsigned int)f2b_bits(u3) << 16);
            *(unsigned long long*)&Wb[c][k] =
                (unsigned long long)p0 | ((unsigned long long)p1 << 32);
        }
    }
    __syncthreads();

    // ---- one-time: pull this thread's 16 B-fragments into registers ----
    const unsigned short* wrow = &Wb[w * 16 + lm][0];
    const int ko = lk * 8;
    const bf16x8 B00 = *(const bf16x8*)&wrow[ 0 * 32 + ko];
    const bf16x8 B01 = *(const bf16x8*)&wrow[ 1 * 32 + ko];
    const bf16x8 B02 = *(const bf16x8*)&wrow[ 2 * 32 + ko];
    const bf16x8 B03 = *(const bf16x8*)&wrow[ 3 * 32 + ko];
    const bf16x8 B04 = *(const bf16x8*)&wrow[ 4 * 32 + ko];
    const bf16x8 B05 = *(const bf16x8*)&wrow[ 5 * 32 + ko];
    const bf16x8 B06 = *(const bf16x8*)&wrow[ 6 * 32 + ko];
    const bf16x8 B07 = *(const bf16x8*)&wrow[ 7 * 32 + ko];
    const bf16x8 B08 = *(const bf16x8*)&wrow[ 8 * 32 + ko];
    const bf16x8 B09 = *(const bf16x8*)&wrow[ 9 * 32 + ko];
    const bf16x8 B10 = *(const bf16x8*)&wrow[10 * 32 + ko];
    const bf16x8 B11 = *(const bf16x8*)&wrow[11 * 32 + ko];
    const bf16x8 B12 = *(const bf16x8*)&wrow[12 * 32 + ko];
    const bf16x8 B13 = *(const bf16x8*)&wrow[13 * 32 + ko];
    const bf16x8 B14 = *(const bf16x8*)&wrow[14 * 32 + ko];
    const bf16x8 B15 = *(const bf16x8*)&wrow[15 * 32 + ko];

    for (int ts = 0; ts < MAXLEN; ++ts) {
        const float* hc = (ts & 1) ? hB : hA;
        float*       hn = (ts & 1) ? hA : hB;

        // ---- stage 16 h rows: fp32 relaxed-agent loads -> bf16 LDS ----
        #pragma unroll
        for (int q = 0; q < 2; ++q) {
            const int chunk = t + q * 512;        // 0..1023
            const int row   = chunk >> 6;         // 0..15
            const int kc    = (chunk & 63) * 8;   // 0..504
            const unsigned long long* src = (const unsigned long long*)
                &hc[(size_t)(r0 + row) * HID + kc];
            unsigned long long d0 = __hip_atomic_load(src + 0,
                __ATOMIC_RELAXED, __HIP_MEMORY_SCOPE_AGENT);
            unsigned long long d1 = __hip_atomic_load(src + 1,
                __ATOMIC_RELAXED, __HIP_MEMORY_SCOPE_AGENT);
            unsigned long long d2 = __hip_atomic_load(src + 2,
                __ATOMIC_RELAXED, __HIP_MEMORY_SCOPE_AGENT);
            unsigned long long d3 = __hip_atomic_load(src + 3,
                __ATOMIC_RELAXED, __HIP_MEMORY_SCOPE_AGENT);
            unsigned int q0 = (unsigned int)f2b_bits((unsigned int)d0) |
                              ((unsigned int)f2b_bits((unsigned int)(d0 >> 32)) << 16);
            unsigned int q1 = (unsigned int)f2b_bits((unsigned int)d1) |
                              ((unsigned int)f2b_bits((unsigned int)(d1 >> 32)) << 16);
            unsigned int q2 = (unsigned int)f2b_bits((unsigned int)d2) |
                              ((unsigned int)f2b_bits((unsigned int)(d2 >> 32)) << 16);
            unsigned int q3 = (unsigned int)f2b_bits((unsigned int)d3) |
                              ((unsigned int)f2b_bits((unsigned int)(d3 >> 32)) << 16);
            *(unsigned long long*)&hsb[row][kc] =
                (unsigned long long)q0 | ((unsigned long long)q1 << 32);
            *(unsigned long long*)&hsb[row][kc + 4] =
                (unsigned long long)q2 | ((unsigned long long)q3 << 32);
        }

        // ---- feedforward gather for this lane's 4 output rows (fp32) ----
        float ev[4];
        #pragma unroll
        for (int i = 0; i < 4; ++i) {
            const int r   = lk * 4 + i;
            const int tok = inputs[(r0 + r) * MAXLEN + ts];
            ev[i] = embW[(size_t)tok * HID + j0 + w * 16 + lm];
        }
        __syncthreads();

        // ---- MFMA: 16 k-tiles, A from hsb, B from registers ----
        f32x4 ae = {0.f, 0.f, 0.f, 0.f};
        f32x4 ao = {0.f, 0.f, 0.f, 0.f};
#define MF2(k0, Ba, Bb)                                                       \
        {                                                                     \
            const bf16x8 a0 = *(const bf16x8*)&hsb[lm][(k0) * 32 + ko];       \
            ae = __builtin_amdgcn_mfma_f32_16x16x32_bf16(a0, Ba, ae, 0, 0, 0);\
            const bf16x8 a1 = *(const bf16x8*)&hsb[lm][(k0 + 1) * 32 + ko];   \
            ao = __builtin_amdgcn_mfma_f32_16x16x32_bf16(a1, Bb, ao, 0, 0, 0);\
        }
        MF2( 0, B00, B01); MF2( 2, B02, B03);
        MF2( 4, B04, B05); MF2( 6, B06, B07);
        MF2( 8, B08, B09); MF2(10, B10, B11);
        MF2(12, B12, B13); MF2(14, B14, B15);
#undef MF2
        const f32x4 cc = ae + ao;

        // ---- tanh + publish (D lane: row = lk*4+i, col = w*16+lm) ----
        #pragma unroll
        for (int i = 0; i < 4; ++i) {
            const float s = tanhf(cc[i] + ev[i]);
            __hip_atomic_store(
                &hn[(size_t)(r0 + lk * 4 + i) * HID + j0 + w * 16 + lm], s,
                __ATOMIC_RELAXED, __HIP_MEMORY_SCOPE_AGENT);
        }
        __syncthreads();   // vmcnt drain: publish stores complete

        // ---- central 4-block barrier (R4/R11-proven protocol) ----
        if (t == 0) {
            int* c = &bar[bgrp * MAXLEN + ts];
            __hip_atomic_fetch_add(c, 1, __ATOMIC_ACQ_REL,
                                   __HIP_MEMORY_SCOPE_AGENT);
            while (__hip_atomic_load(c, __ATOMIC_ACQUIRE,
                                     __HIP_MEMORY_SCOPE_AGENT) < NJG) {
                __builtin_amdgcn_s_sleep(1);
            }
        }
        __syncthreads();
    }
    // final h in hA (MAXLEN even)
}

// ---------------------------------------------------------------------------
// Kernel C: logits = hA @ W_out + b_out, sigmoid. Tiny. (fp32, unchanged)
// ---------------------------------------------------------------------------
__global__ void head_kernel(const float* __restrict__ h_final,
                            const float* __restrict__ W_out,
                            const float* __restrict__ b_out,
                            float* __restrict__ out)
{
    const int t = threadIdx.x;
    const int b = t >> 1, c = t & 1;
    float acc = b_out[c];
    for (int k = 0; k < HID; ++k)
        acc = fmaf(h_final[(size_t)b * HID + k], W_out[k * NCLASS + c], acc);
    out[t] = 1.f / (1.f + expf(-acc));
}

// ---------------------------------------------------------------------------
extern "C" void kernel_launch(void* const* d_in, const int* in_sizes, int n_in,
                              void* d_out, int out_size, void* d_ws,
                              size_t ws_size, hipStream_t stream)
{
    const int*   inputs = (const int*)  d_in[0];
    const float* emb    = (const float*)d_in[1];
    const float* W_ih   = (const float*)d_in[2];
    const float* W_hh   = (const float*)d_in[3];
    const float* b_h    = (const float*)d_in[4];
    const float* W_out  = (const float*)d_in[5];
    const float* b_out  = (const float*)d_in[6];
    float* out = (float*)d_out;

    // ws layout: embW 64 MB | hA 256 KB | hB 256 KB | bar 16 KB
    float* embW = (float*)d_ws;
    float* hA   = embW + (size_t)VOCAB * HID;
    float* hB   = hA + (size_t)BATCH * HID;
    int*   bar  = (int*)(hB + (size_t)BATCH * HID);

    // per-launch re-init (graph-capture-safe, deterministic)
    hipMemsetAsync(hA, 0, (size_t)BATCH * HID * sizeof(float), stream);
    hipMemsetAsync(bar, 0, (size_t)NBG * MAXLEN * sizeof(int), stream);

    embw_kernel<<<VOCAB / 64, 256, 0, stream>>>(emb, W_ih, b_h, embW);
    rnn_kernel<<<NBG * NJG, 512, 0, stream>>>(inputs, embW, W_hh,
                                              hA, hB, bar);
    head_kernel<<<1, 256, 0, stream>>>(hA, W_out, b_out, out);
}